// Round 13
// baseline (149.667 us; speedup 1.0000x reference)
//
#include <hip/hip_runtime.h>

#define TT 2048
#define DD 1024
#define NHH 8
#define DKK 128
// softmax in log2 domain: v_exp_f32 is natively 2^x
#define SCALE2 0.1275174724f          /* (1/sqrt(128)) * log2(e) */

typedef __attribute__((ext_vector_type(8)))  short short8;
typedef __attribute__((ext_vector_type(4)))  short short4v;
typedef __attribute__((ext_vector_type(4)))  float float4v;
typedef __attribute__((ext_vector_type(16))) float float16v;
typedef __attribute__((ext_vector_type(4)))  int   int4v;

__device__ __forceinline__ short f2bf(float f) {
  union { float f; unsigned u; } v; v.f = f;
  unsigned r = v.u + 0x7FFFu + ((v.u >> 16) & 1u);
  return (short)(r >> 16);
}
__device__ __forceinline__ unsigned cvtpk(float lo, float hi) {
  unsigned r;
  asm("v_cvt_pk_bf16_f32 %0, %1, %2" : "=v"(r) : "v"(lo), "v"(hi));
  return r;
}
// pairwise exchange lane l <-> l^32 (VALU pipe, not LDS)
__device__ __forceinline__ float xhalf_add(float x) {
  float y;
  asm("v_mov_b32 %0, %1" : "=v"(y) : "v"(x));
  asm("v_permlane32_swap_b32 %0, %1" : "+v"(x), "+v"(y));
  return x + y;
}
// 16-chunk swizzle for 256B rows
__device__ __forceinline__ int s4(int row) {
  return (row & 7) ^ (((row >> 3) & 3) << 2);
}
// async global->LDS, 16B per lane; lds base is wave-uniform, gsrc per-lane
__device__ __forceinline__ void gl2lds(const void* g, void* l) {
  __builtin_amdgcn_global_load_lds(
      (const __attribute__((address_space(1))) void*)g,
      (__attribute__((address_space(3))) void*)l, 16, 0, 0);
}

// ---- fused prep: xt transpose+cast (blocks 0..8191), Wq cast (8192..9215),
// ---- Wo cast (9216..10239) ----
__global__ __launch_bounds__(256) void k_prep(const float* __restrict__ x,
                                              short* __restrict__ xt,
                                              const float* __restrict__ Wq,
                                              short* __restrict__ wqb,
                                              const float* __restrict__ Wo,
                                              short* __restrict__ wob) {
  int id = blockIdx.x;
  if (id < 8192) {
    __shared__ float tile[32][33];
    int ttile = id & 63, dtile = (id >> 6) & 31, b = id >> 11;
    int d0 = dtile << 5, t0 = ttile << 5;
    int tx = threadIdx.x & 31, ty = threadIdx.x >> 5;
    const float* xp = x + ((size_t)b * DD + d0) * TT + t0;
#pragma unroll
    for (int yy = 0; yy < 32; yy += 8)
      tile[ty + yy][tx] = xp[(size_t)(ty + yy) * TT + tx];
    __syncthreads();
    short* op = xt + ((size_t)b * TT + t0) * DD + d0;
#pragma unroll
    for (int yy = 0; yy < 32; yy += 8)
      op[(size_t)(ty + yy) * DD + tx] = f2bf(tile[tx][ty + yy]);
  } else {
    const float* w = (id < 9216) ? Wq : Wo;
    short* o = (id < 9216) ? wqb : wob;
    int i = (id - 8192 - ((id < 9216) ? 0 : 1024)) * 256 + threadIdx.x;
    float4v v = ((const float4v*)w)[i];
    short4v s;
#pragma unroll
    for (int j = 0; j < 4; ++j) s[j] = f2bf(v[j]);
    ((short4v*)o)[i] = s;
  }
}

// ---- GEMM: C = A(M x 1024) * Bt(N x 1024)^T  — m97 recipe ----
// EPI 0: writes qb (row-major bf16) AND qhT (transposed bf16) via LDS Ct.
// EPI 1: C f32 at out[(b*1024 + m)*2048 + (n & 2047)].
template <int EPI>
__global__ __launch_bounds__(256) void k_gemm(const short* __restrict__ A,
                                              const short* __restrict__ Bt,
                                              void* __restrict__ Cout,
                                              short* __restrict__ qhT) {
  __shared__ __align__(16) short As[128 * 64];
  __shared__ __align__(16) short Bs[128 * 64];
  __shared__ __align__(16) short Ct[(EPI == 0) ? 128 * 136 : 1];
  const int K = 1024;
  int tm = blockIdx.x * 128, tn = blockIdx.y * 128;
  int tid = threadIdx.x, lane = tid & 63, w = tid >> 6;
  int wm = (w >> 1) * 64, wn = (w & 1) * 64;
  int ql = lane & 15, g = lane >> 4;

  int srow[4], scol[4];
#pragma unroll
  for (int c = 0; c < 4; ++c) {
    int cg = w * 4 + c;
    int r = cg * 8 + (lane >> 3);
    srow[c] = r;
    scol[c] = ((lane & 7) ^ (r & 7)) * 8;
  }

  float4v acc[4][4];
#pragma unroll
  for (int mt = 0; mt < 4; ++mt)
#pragma unroll
    for (int nt = 0; nt < 4; ++nt) acc[mt][nt] = (float4v){0.f, 0.f, 0.f, 0.f};

  for (int k0 = 0; k0 < K; k0 += 64) {
    __syncthreads();
#pragma unroll
    for (int c = 0; c < 4; ++c) {
      int cg = w * 4 + c;
      gl2lds(A + (size_t)(tm + srow[c]) * K + k0 + scol[c], As + cg * 512);
      gl2lds(Bt + (size_t)(tn + srow[c]) * K + k0 + scol[c], Bs + cg * 512);
    }
    __syncthreads();
#pragma unroll
    for (int k4 = 0; k4 < 2; ++k4) {
      short8 af[4], bfr[4];
#pragma unroll
      for (int mt = 0; mt < 4; ++mt) {
        int row = wm + mt * 16 + ql;
        af[mt] = *(const short8*)(As + row * 64 + (((k4 * 4 + g) ^ (ql & 7)) * 8));
      }
#pragma unroll
      for (int nt = 0; nt < 4; ++nt) {
        int row = wn + nt * 16 + ql;
        bfr[nt] = *(const short8*)(Bs + row * 64 + (((k4 * 4 + g) ^ (ql & 7)) * 8));
      }
#pragma unroll
      for (int mt = 0; mt < 4; ++mt)
#pragma unroll
        for (int nt = 0; nt < 4; ++nt)
          acc[mt][nt] = __builtin_amdgcn_mfma_f32_16x16x32_bf16(af[mt], bfr[nt],
                                                                acc[mt][nt], 0, 0, 0);
    }
  }

  if (EPI == 1) {
#pragma unroll
    for (int mt = 0; mt < 4; ++mt)
#pragma unroll
      for (int nt = 0; nt < 4; ++nt)
#pragma unroll
        for (int r = 0; r < 4; ++r) {
          int m = tm + wm + mt * 16 + g * 4 + r;
          int n = tn + wn + nt * 16 + ql;
          int b = n >> 11, t = n & 2047;
          ((float*)Cout)[((size_t)b * 1024 + m) * 2048 + t] = acc[mt][nt][r];
        }
  } else {
    // stage C-tile into LDS (bf16), then emit qb + qhT coalesced
    __syncthreads();   // As/Bs done... (Ct is separate; sync for Ct readers below)
#pragma unroll
    for (int mt = 0; mt < 4; ++mt)
#pragma unroll
      for (int nt = 0; nt < 4; ++nt)
#pragma unroll
        for (int r = 0; r < 4; ++r)
          Ct[(wm + mt * 16 + g * 4 + r) * 136 + wn + nt * 16 + ql] =
              f2bf(acc[mt][nt][r]);
    __syncthreads();
    int bb = tm >> 11, t0 = tm & 2047;
    short* qb = (short*)Cout;
    // qb: thread t -> row m=t>>1, cols (t&1)*64 + i*8
    {
      int m = tid >> 1, c0 = (tid & 1) * 64;
      short* dst = qb + (size_t)(tm + m) * 1024 + tn + c0;
      const short* src = Ct + m * 136 + c0;
#pragma unroll
      for (int i = 0; i < 8; ++i)
        *(short8*)(dst + i * 8) = *(const short8*)(src + i * 8);
    }
    // qhT: thread t -> row n=t>>1, cols (t&1)*64 + i*8 (read Ct column n)
    {
      int n = tid >> 1, m0 = (tid & 1) * 64;
      short* dst = qhT + ((size_t)(bb * DD + tn + n)) * TT + t0 + m0;
#pragma unroll
      for (int i = 0; i < 8; ++i) {
        short8 v;
#pragma unroll
        for (int j = 0; j < 8; ++j) v[j] = Ct[(m0 + i * 8 + j) * 136 + n];
        *(short8*)(dst + i * 8) = v;
      }
    }
  }
}

// ---- fused masked self-attention (R10/R12 version, measured 82.8 us) ----
__global__ __launch_bounds__(256, 2) void k_attn(const short* __restrict__ q,
                                                 const short* __restrict__ qhT,
                                                 const float* __restrict__ mask,
                                                 short* __restrict__ ctx) {
  __shared__ __align__(16) short Ks[2][64 * 128];
  __shared__ __align__(16) short Vt[2][128 * 64];
  __shared__ __align__(16) short Kx[2][64 * 16];

  int qt = blockIdx.x, bh = blockIdx.y;
  int b = bh >> 3, h = bh & 7;
  int tid = threadIdx.x, lane = tid & 63, w = tid >> 6;
  int ql32 = lane & 31, hi = lane >> 5;
  int csw = s4(ql32);
  int vsw = ql32 & 7;
  short negbig = f2bf(-1e30f);

  int qrow = qt * 128 + w * 32 + ql32;
  const short* qp = q + ((size_t)(b * TT + qrow)) * DD + h * DKK;
  short8 qf[8];
#pragma unroll
  for (int kc8 = 0; kc8 < 8; ++kc8)
    qf[kc8] = *(const short8*)(qp + kc8 * 16 + hi * 8);
  float rm = mask[(size_t)b * TT + qrow];

  float qs = SCALE2 * rm;
#pragma unroll
  for (int kc8 = 0; kc8 < 8; ++kc8) {
    union { short8 s; unsigned u[4]; } a;
    a.s = qf[kc8];
#pragma unroll
    for (int j = 0; j < 4; ++j) {
      union { unsigned u; float f; } lo, hh;
      lo.u = a.u[j] << 16;
      hh.u = a.u[j] & 0xFFFF0000u;
      a.u[j] = cvtpk(lo.f * qs, hh.f * qs);
    }
    qf[kc8] = a.s;
  }
  short8 bext = (short8)0;
  if (hi == 0) bext[0] = (rm != 0.f) ? (short)0x3F80 : (short)0;

  int oc = tid & 15, r2 = tid >> 4;
  const short* kbase_g = q + ((size_t)b * TT) * DD + h * DKK + oc * 8;
  const short* vbase_g = qhT + ((size_t)(b * DD + h * DKK)) * TT;
  int vd[4], vko[4], vwoff[4];
#pragma unroll
  for (int p = 0; p < 4; ++p) {
    int idx = p * 256 + tid;
    vd[p] = idx >> 3;
    vko[p] = idx & 7;
    vwoff[p] = vd[p] * 64 + ((vko[p] ^ (vd[p] & 7)) * 8);
  }
  int kwoff[2][2];
#pragma unroll
  for (int ps = 0; ps < 2; ++ps) {
    int ra = 2 * r2 + 32 * ps, rb = ra + 1;
    kwoff[ps][0] = ra * 128 + ((oc ^ s4(ra)) * 8);
    kwoff[ps][1] = rb * 128 + ((oc ^ s4(rb)) * 8);
  }

  short8 va[2], vb[2], vv[4];
#pragma unroll
  for (int ps = 0; ps < 2; ++ps) {
    const short* kp = kbase_g + (size_t)(2 * r2 + 32 * ps) * DD;
    va[ps] = *(const short8*)(kp);
    vb[ps] = *(const short8*)(kp + DD);
  }
#pragma unroll
  for (int p = 0; p < 4; ++p)
    vv[p] = *(const short8*)(vbase_g + (size_t)vd[p] * TT + vko[p] * 8);
  float mreg = mask[(size_t)b * TT + lane];

#pragma unroll
  for (int ps = 0; ps < 2; ++ps) {
    *(short8*)(Ks[0] + kwoff[ps][0]) = va[ps];
    *(short8*)(Ks[0] + kwoff[ps][1]) = vb[ps];
  }
#pragma unroll
  for (int p = 0; p < 4; ++p)
    *(short8*)(Vt[0] + vwoff[p]) = vv[p];
  if (tid < 128) {
    short8 z = (short8)0;
    if (tid < 64) z[0] = (mreg != 0.f) ? (short)0 : negbig;
    *(short8*)(&Kx[0][0] + tid * 16) = z;
    *(short8*)(&Kx[0][0] + tid * 16 + 8) = (short8)0;
  }

  float l_run = 0.f;
  float16v o[4];
#pragma unroll
  for (int nt = 0; nt < 4; ++nt)
#pragma unroll
    for (int r = 0; r < 16; ++r) o[nt][r] = 0.f;

  for (int kt = 0; kt < 32; ++kt) {
    int cur = kt & 1;
    const short* ksb = Ks[cur];
    const short* vtb = Vt[cur];
    const short* kxb = Kx[cur];
    short* ksn = Ks[cur ^ 1];
    short* vtn = Vt[cur ^ 1];
    short* kxn = Kx[cur ^ 1];

    __syncthreads();

    if (kt < 31) {
      int kb0n = (kt + 1) * 64;
      const short* kpn = kbase_g + (size_t)kb0n * DD;
#pragma unroll
      for (int ps = 0; ps < 2; ++ps) {
        const short* kp = kpn + (size_t)(2 * r2 + 32 * ps) * DD;
        va[ps] = *(const short8*)(kp);
        vb[ps] = *(const short8*)(kp + DD);
      }
#pragma unroll
      for (int p = 0; p < 4; ++p)
        vv[p] = *(const short8*)(vbase_g + (size_t)vd[p] * TT + kb0n + vko[p] * 8);
      mreg = mask[(size_t)b * TT + kb0n + lane];
    }

    float16v st0, st1;
#pragma unroll
    for (int r = 0; r < 16; ++r) { st0[r] = 0.f; st1[r] = 0.f; }
    __builtin_amdgcn_s_setprio(1);
    {
      short8 ax0 = *(const short8*)(kxb + ql32 * 16 + hi * 8);
      short8 ax1 = *(const short8*)(kxb + (32 + ql32) * 16 + hi * 8);
      st0 = __builtin_amdgcn_mfma_f32_32x32x16_bf16(ax0, bext, st0, 0, 0, 0);
      st1 = __builtin_amdgcn_mfma_f32_32x32x16_bf16(ax1, bext, st1, 0, 0, 0);
    }
#pragma unroll
    for (int kc8 = 0; kc8 < 8; ++kc8) {
      int csk = ((kc8 * 2 + hi) ^ csw) * 8;
      short8 kf0 = *(const short8*)(ksb + ql32 * 128 + csk);
      short8 kf1 = *(const short8*)(ksb + (32 + ql32) * 128 + csk);
      st0 = __builtin_amdgcn_mfma_f32_32x32x16_bf16(kf0, qf[kc8], st0, 0, 0, 0);
      st1 = __builtin_amdgcn_mfma_f32_32x32x16_bf16(kf1, qf[kc8], st1, 0, 0, 0);
    }
    __builtin_amdgcn_s_setprio(0);

    float tsum = 0.f;
#pragma unroll
    for (int r = 0; r < 16; ++r) {
      float p0 = __builtin_amdgcn_exp2f(st0[r]);
      float p1 = __builtin_amdgcn_exp2f(st1[r]);
      st0[r] = p0; st1[r] = p1;
      tsum += p0 + p1;
    }
    l_run += xhalf_add(tsum);

    short8 pa[4];
#pragma unroll
    for (int kc = 0; kc < 4; ++kc) {
      int a0 = 2 * (kc & 1);
      unsigned x0, x1, y0, y1;
      if (kc < 2) {
        x0 = cvtpk(st0[4 * a0 + 0], st0[4 * a0 + 1]);
        x1 = cvtpk(st0[4 * a0 + 2], st0[4 * a0 + 3]);
        y0 = cvtpk(st0[4 * a0 + 4], st0[4 * a0 + 5]);
        y1 = cvtpk(st0[4 * a0 + 6], st0[4 * a0 + 7]);
      } else {
        x0 = cvtpk(st1[4 * a0 + 0], st1[4 * a0 + 1]);
        x1 = cvtpk(st1[4 * a0 + 2], st1[4 * a0 + 3]);
        y0 = cvtpk(st1[4 * a0 + 4], st1[4 * a0 + 5]);
        y1 = cvtpk(st1[4 * a0 + 6], st1[4 * a0 + 7]);
      }
      asm("v_permlane32_swap_b32 %0, %1" : "+v"(x0), "+v"(y0));
      asm("v_permlane32_swap_b32 %0, %1" : "+v"(x1), "+v"(y1));
      union { unsigned u[4]; short8 s8; } pu;
      pu.u[0] = x0; pu.u[1] = x1; pu.u[2] = y0; pu.u[3] = y1;
      pa[kc] = pu.s8;
    }

    __builtin_amdgcn_s_setprio(1);
#pragma unroll
    for (int nt = 0; nt < 4; ++nt) {
      int row = nt * 32 + ql32;
#pragma unroll
      for (int kc = 0; kc < 4; ++kc) {
        short8 vf = *(const short8*)(vtb + row * 64 + (((kc * 2 + hi) ^ vsw) * 8));
        o[nt] = __builtin_amdgcn_mfma_f32_32x32x16_bf16(vf, pa[kc], o[nt], 0, 0, 0);
      }
    }
    __builtin_amdgcn_s_setprio(0);

    if (kt < 31) {
#pragma unroll
      for (int ps = 0; ps < 2; ++ps) {
        *(short8*)(ksn + kwoff[ps][0]) = va[ps];
        *(short8*)(ksn + kwoff[ps][1]) = vb[ps];
      }
#pragma unroll
      for (int p = 0; p < 4; ++p)
        *(short8*)(vtn + vwoff[p]) = vv[p];
      if (tid < 64) {
        unsigned word = (mreg != 0.f) ? 0u : (unsigned)(unsigned short)negbig;
        *(unsigned*)(kxn + tid * 16) = word;
      }
    }
  }

  float il = 1.0f / l_run;
  short* cp = ctx + ((size_t)(b * TT + qrow)) * DD + h * DKK;
#pragma unroll
  for (int nt = 0; nt < 4; ++nt)
#pragma unroll
    for (int a = 0; a < 4; ++a) {
      short4v sv;
#pragma unroll
      for (int j = 0; j < 4; ++j) sv[j] = f2bf(o[nt][4 * a + j] * il);
      *(short4v*)(cp + nt * 32 + 8 * a + 4 * hi) = sv;
    }
}

extern "C" void kernel_launch(void* const* d_in, const int* in_sizes, int n_in,
                              void* d_out, int out_size, void* d_ws, size_t ws_size,
                              hipStream_t stream) {
  const float* x    = (const float*)d_in[0];
  const float* mask = (const float*)d_in[1];
  const float* Wq   = (const float*)d_in[2];
  const float* Wo   = (const float*)d_in[3];
  char* ws = (char*)d_ws;
  short* xt  = (short*)(ws);                              // 16 MB (reused as qhT)
  short* wqb = (short*)(ws + (size_t)16 * 1024 * 1024);
  short* wob = (short*)(ws + (size_t)18 * 1024 * 1024);
  short* qb  = (short*)(ws + (size_t)20 * 1024 * 1024);
  short* ctx = (short*)(ws + (size_t)36 * 1024 * 1024);
  short* qhT = (short*)(ws + (size_t)52 * 1024 * 1024);   // separate (xt still live in gemm<0>)

  k_prep<<<10240, 256, 0, stream>>>(x, xt, Wq, wqb, Wo, wob);
  k_gemm<0><<<dim3(64, 8), 256, 0, stream>>>(xt, wqb, qb, qhT);
  k_attn<<<dim3(16, 32), 256, 0, stream>>>(qb, qhT, mask, ctx);
  k_gemm<1><<<dim3(8, 64), 256, 0, stream>>>(wob, ctx, d_out, nullptr);
}

// Round 14
// 146.218 us; speedup vs baseline: 1.0236x; 1.0236x over previous
//
#include <hip/hip_runtime.h>

#define TT 2048
#define DD 1024
#define NHH 8
#define DKK 128
// softmax in log2 domain: v_exp_f32 is natively 2^x
#define SCALE2 0.1275174724f          /* (1/sqrt(128)) * log2(e) */

typedef __attribute__((ext_vector_type(8)))  short short8;
typedef __attribute__((ext_vector_type(4)))  short short4v;
typedef __attribute__((ext_vector_type(4)))  float float4v;
typedef __attribute__((ext_vector_type(16))) float float16v;
typedef __attribute__((ext_vector_type(4)))  int   int4v;

__device__ __forceinline__ short f2bf(float f) {
  union { float f; unsigned u; } v; v.f = f;
  unsigned r = v.u + 0x7FFFu + ((v.u >> 16) & 1u);
  return (short)(r >> 16);
}
__device__ __forceinline__ unsigned cvtpk(float lo, float hi) {
  unsigned r;
  asm("v_cvt_pk_bf16_f32 %0, %1, %2" : "=v"(r) : "v"(lo), "v"(hi));
  return r;
}
// pairwise exchange lane l <-> l^32 (VALU pipe, not LDS)
__device__ __forceinline__ float xhalf_add(float x) {
  float y;
  asm("v_mov_b32 %0, %1" : "=v"(y) : "v"(x));
  asm("v_permlane32_swap_b32 %0, %1" : "+v"(x), "+v"(y));
  return x + y;
}
// 16-chunk swizzle for 256B rows
__device__ __forceinline__ int s4(int row) {
  return (row & 7) ^ (((row >> 3) & 3) << 2);
}
// async global->LDS, 16B per lane; lds base is wave-uniform, gsrc per-lane
__device__ __forceinline__ void gl2lds(const void* g, void* l) {
  __builtin_amdgcn_global_load_lds(
      (const __attribute__((address_space(1))) void*)g,
      (__attribute__((address_space(3))) void*)l, 16, 0, 0);
}

// ---- fused prep: xt transpose+cast (blocks 0..8191), Wq cast (8192..9215),
// ---- Wo cast (9216..10239) ----
__global__ __launch_bounds__(256) void k_prep(const float* __restrict__ x,
                                              short* __restrict__ xt,
                                              const float* __restrict__ Wq,
                                              short* __restrict__ wqb,
                                              const float* __restrict__ Wo,
                                              short* __restrict__ wob) {
  int id = blockIdx.x;
  if (id < 8192) {
    __shared__ float tile[32][33];
    int ttile = id & 63, dtile = (id >> 6) & 31, b = id >> 11;
    int d0 = dtile << 5, t0 = ttile << 5;
    int tx = threadIdx.x & 31, ty = threadIdx.x >> 5;
    const float* xp = x + ((size_t)b * DD + d0) * TT + t0;
#pragma unroll
    for (int yy = 0; yy < 32; yy += 8)
      tile[ty + yy][tx] = xp[(size_t)(ty + yy) * TT + tx];
    __syncthreads();
    short* op = xt + ((size_t)b * TT + t0) * DD + d0;
#pragma unroll
    for (int yy = 0; yy < 32; yy += 8)
      op[(size_t)(ty + yy) * DD + tx] = f2bf(tile[tx][ty + yy]);
  } else {
    const float* w = (id < 9216) ? Wq : Wo;
    short* o = (id < 9216) ? wqb : wob;
    int i = (id - 8192 - ((id < 9216) ? 0 : 1024)) * 256 + threadIdx.x;
    float4v v = ((const float4v*)w)[i];
    short4v s;
#pragma unroll
    for (int j = 0; j < 4; ++j) s[j] = f2bf(v[j]);
    ((short4v*)o)[i] = s;
  }
}

// ---- GEMM: C = A(M x 1024) * Bt(N x 1024)^T  — m97 recipe ----
// EPI 0: writes qb (row-major bf16) AND qhT (transposed bf16) via LDS Ct.
// EPI 1: C f32 at out[(b*1024 + m)*2048 + (n & 2047)].
template <int EPI>
__global__ __launch_bounds__(256) void k_gemm(const short* __restrict__ A,
                                              const short* __restrict__ Bt,
                                              void* __restrict__ Cout,
                                              short* __restrict__ qhT) {
  __shared__ __align__(16) short As[128 * 64];
  __shared__ __align__(16) short Bs[128 * 64];
  __shared__ __align__(16) short Ct[(EPI == 0) ? 128 * 136 : 1];
  const int K = 1024;
  int tm = blockIdx.x * 128, tn = blockIdx.y * 128;
  int tid = threadIdx.x, lane = tid & 63, w = tid >> 6;
  int wm = (w >> 1) * 64, wn = (w & 1) * 64;
  int ql = lane & 15, g = lane >> 4;

  int srow[4], scol[4];
#pragma unroll
  for (int c = 0; c < 4; ++c) {
    int cg = w * 4 + c;
    int r = cg * 8 + (lane >> 3);
    srow[c] = r;
    scol[c] = ((lane & 7) ^ (r & 7)) * 8;
  }

  float4v acc[4][4];
#pragma unroll
  for (int mt = 0; mt < 4; ++mt)
#pragma unroll
    for (int nt = 0; nt < 4; ++nt) acc[mt][nt] = (float4v){0.f, 0.f, 0.f, 0.f};

  for (int k0 = 0; k0 < K; k0 += 64) {
    __syncthreads();
#pragma unroll
    for (int c = 0; c < 4; ++c) {
      int cg = w * 4 + c;
      gl2lds(A + (size_t)(tm + srow[c]) * K + k0 + scol[c], As + cg * 512);
      gl2lds(Bt + (size_t)(tn + srow[c]) * K + k0 + scol[c], Bs + cg * 512);
    }
    __syncthreads();
#pragma unroll
    for (int k4 = 0; k4 < 2; ++k4) {
      short8 af[4], bfr[4];
#pragma unroll
      for (int mt = 0; mt < 4; ++mt) {
        int row = wm + mt * 16 + ql;
        af[mt] = *(const short8*)(As + row * 64 + (((k4 * 4 + g) ^ (ql & 7)) * 8));
      }
#pragma unroll
      for (int nt = 0; nt < 4; ++nt) {
        int row = wn + nt * 16 + ql;
        bfr[nt] = *(const short8*)(Bs + row * 64 + (((k4 * 4 + g) ^ (ql & 7)) * 8));
      }
#pragma unroll
      for (int mt = 0; mt < 4; ++mt)
#pragma unroll
        for (int nt = 0; nt < 4; ++nt)
          acc[mt][nt] = __builtin_amdgcn_mfma_f32_16x16x32_bf16(af[mt], bfr[nt],
                                                                acc[mt][nt], 0, 0, 0);
    }
  }

  if (EPI == 1) {
#pragma unroll
    for (int mt = 0; mt < 4; ++mt)
#pragma unroll
      for (int nt = 0; nt < 4; ++nt)
#pragma unroll
        for (int r = 0; r < 4; ++r) {
          int m = tm + wm + mt * 16 + g * 4 + r;
          int n = tn + wn + nt * 16 + ql;
          int b = n >> 11, t = n & 2047;
          ((float*)Cout)[((size_t)b * 1024 + m) * 2048 + t] = acc[mt][nt][r];
        }
  } else {
    // stage C-tile into LDS (bf16), then emit qb + qhT coalesced
    __syncthreads();
#pragma unroll
    for (int mt = 0; mt < 4; ++mt)
#pragma unroll
      for (int nt = 0; nt < 4; ++nt)
#pragma unroll
        for (int r = 0; r < 4; ++r)
          Ct[(wm + mt * 16 + g * 4 + r) * 136 + wn + nt * 16 + ql] =
              f2bf(acc[mt][nt][r]);
    __syncthreads();
    int bb = tm >> 11, t0 = tm & 2047;
    short* qb = (short*)Cout;
    {
      int m = tid >> 1, c0 = (tid & 1) * 64;
      short* dst = qb + (size_t)(tm + m) * 1024 + tn + c0;
      const short* src = Ct + m * 136 + c0;
#pragma unroll
      for (int i = 0; i < 8; ++i)
        *(short8*)(dst + i * 8) = *(const short8*)(src + i * 8);
    }
    {
      int n = tid >> 1, m0 = (tid & 1) * 64;
      short* dst = qhT + ((size_t)(bb * DD + tn + n)) * TT + t0 + m0;
#pragma unroll
      for (int i = 0; i < 8; ++i) {
        short8 v;
#pragma unroll
        for (int j = 0; j < 8; ++j) v[j] = Ct[(m0 + i * 8 + j) * 136 + n];
        *(short8*)(dst + i * 8) = v;
      }
    }
  }
}

// ---- fused masked self-attention (R12 body; grid now (bh, qt) for XCD-L2
// ---- locality: linear block id % 8 == bh % 8 -> each XCD hosts 4 (b,h)
// ---- groups = 4MB K/V working set = L2-resident) ----
__global__ __launch_bounds__(256, 2) void k_attn(const short* __restrict__ q,
                                                 const short* __restrict__ qhT,
                                                 const float* __restrict__ mask,
                                                 short* __restrict__ ctx) {
  __shared__ __align__(16) short Ks[2][64 * 128];
  __shared__ __align__(16) short Vt[2][128 * 64];
  __shared__ __align__(16) short Kx[2][64 * 16];

  int bh = blockIdx.x, qt = blockIdx.y;   // SWAPPED (was qt=x, bh=y)
  int b = bh >> 3, h = bh & 7;
  int tid = threadIdx.x, lane = tid & 63, w = tid >> 6;
  int ql32 = lane & 31, hi = lane >> 5;
  int csw = s4(ql32);
  int vsw = ql32 & 7;
  short negbig = f2bf(-1e30f);

  int qrow = qt * 128 + w * 32 + ql32;
  const short* qp = q + ((size_t)(b * TT + qrow)) * DD + h * DKK;
  short8 qf[8];
#pragma unroll
  for (int kc8 = 0; kc8 < 8; ++kc8)
    qf[kc8] = *(const short8*)(qp + kc8 * 16 + hi * 8);
  float rm = mask[(size_t)b * TT + qrow];

  float qs = SCALE2 * rm;
#pragma unroll
  for (int kc8 = 0; kc8 < 8; ++kc8) {
    union { short8 s; unsigned u[4]; } a;
    a.s = qf[kc8];
#pragma unroll
    for (int j = 0; j < 4; ++j) {
      union { unsigned u; float f; } lo, hh;
      lo.u = a.u[j] << 16;
      hh.u = a.u[j] & 0xFFFF0000u;
      a.u[j] = cvtpk(lo.f * qs, hh.f * qs);
    }
    qf[kc8] = a.s;
  }
  short8 bext = (short8)0;
  if (hi == 0) bext[0] = (rm != 0.f) ? (short)0x3F80 : (short)0;

  int oc = tid & 15, r2 = tid >> 4;
  const short* kbase_g = q + ((size_t)b * TT) * DD + h * DKK + oc * 8;
  const short* vbase_g = qhT + ((size_t)(b * DD + h * DKK)) * TT;
  int vd[4], vko[4], vwoff[4];
#pragma unroll
  for (int p = 0; p < 4; ++p) {
    int idx = p * 256 + tid;
    vd[p] = idx >> 3;
    vko[p] = idx & 7;
    vwoff[p] = vd[p] * 64 + ((vko[p] ^ (vd[p] & 7)) * 8);
  }
  int kwoff[2][2];
#pragma unroll
  for (int ps = 0; ps < 2; ++ps) {
    int ra = 2 * r2 + 32 * ps, rb = ra + 1;
    kwoff[ps][0] = ra * 128 + ((oc ^ s4(ra)) * 8);
    kwoff[ps][1] = rb * 128 + ((oc ^ s4(rb)) * 8);
  }

  short8 va[2], vb[2], vv[4];
#pragma unroll
  for (int ps = 0; ps < 2; ++ps) {
    const short* kp = kbase_g + (size_t)(2 * r2 + 32 * ps) * DD;
    va[ps] = *(const short8*)(kp);
    vb[ps] = *(const short8*)(kp + DD);
  }
#pragma unroll
  for (int p = 0; p < 4; ++p)
    vv[p] = *(const short8*)(vbase_g + (size_t)vd[p] * TT + vko[p] * 8);
  float mreg = mask[(size_t)b * TT + lane];

#pragma unroll
  for (int ps = 0; ps < 2; ++ps) {
    *(short8*)(Ks[0] + kwoff[ps][0]) = va[ps];
    *(short8*)(Ks[0] + kwoff[ps][1]) = vb[ps];
  }
#pragma unroll
  for (int p = 0; p < 4; ++p)
    *(short8*)(Vt[0] + vwoff[p]) = vv[p];
  if (tid < 128) {
    short8 z = (short8)0;
    if (tid < 64) z[0] = (mreg != 0.f) ? (short)0 : negbig;
    *(short8*)(&Kx[0][0] + tid * 16) = z;
    *(short8*)(&Kx[0][0] + tid * 16 + 8) = (short8)0;
  }

  float l_run = 0.f;
  float16v o[4];
#pragma unroll
  for (int nt = 0; nt < 4; ++nt)
#pragma unroll
    for (int r = 0; r < 16; ++r) o[nt][r] = 0.f;

  for (int kt = 0; kt < 32; ++kt) {
    int cur = kt & 1;
    const short* ksb = Ks[cur];
    const short* vtb = Vt[cur];
    const short* kxb = Kx[cur];
    short* ksn = Ks[cur ^ 1];
    short* vtn = Vt[cur ^ 1];
    short* kxn = Kx[cur ^ 1];

    __syncthreads();

    if (kt < 31) {
      int kb0n = (kt + 1) * 64;
      const short* kpn = kbase_g + (size_t)kb0n * DD;
#pragma unroll
      for (int ps = 0; ps < 2; ++ps) {
        const short* kp = kpn + (size_t)(2 * r2 + 32 * ps) * DD;
        va[ps] = *(const short8*)(kp);
        vb[ps] = *(const short8*)(kp + DD);
      }
#pragma unroll
      for (int p = 0; p < 4; ++p)
        vv[p] = *(const short8*)(vbase_g + (size_t)vd[p] * TT + kb0n + vko[p] * 8);
      mreg = mask[(size_t)b * TT + kb0n + lane];
    }

    float16v st0, st1;
#pragma unroll
    for (int r = 0; r < 16; ++r) { st0[r] = 0.f; st1[r] = 0.f; }
    __builtin_amdgcn_s_setprio(1);
    {
      short8 ax0 = *(const short8*)(kxb + ql32 * 16 + hi * 8);
      short8 ax1 = *(const short8*)(kxb + (32 + ql32) * 16 + hi * 8);
      st0 = __builtin_amdgcn_mfma_f32_32x32x16_bf16(ax0, bext, st0, 0, 0, 0);
      st1 = __builtin_amdgcn_mfma_f32_32x32x16_bf16(ax1, bext, st1, 0, 0, 0);
    }
#pragma unroll
    for (int kc8 = 0; kc8 < 8; ++kc8) {
      int csk = ((kc8 * 2 + hi) ^ csw) * 8;
      short8 kf0 = *(const short8*)(ksb + ql32 * 128 + csk);
      short8 kf1 = *(const short8*)(ksb + (32 + ql32) * 128 + csk);
      st0 = __builtin_amdgcn_mfma_f32_32x32x16_bf16(kf0, qf[kc8], st0, 0, 0, 0);
      st1 = __builtin_amdgcn_mfma_f32_32x32x16_bf16(kf1, qf[kc8], st1, 0, 0, 0);
    }
    __builtin_amdgcn_s_setprio(0);

    float tsum = 0.f;
#pragma unroll
    for (int r = 0; r < 16; ++r) {
      float p0 = __builtin_amdgcn_exp2f(st0[r]);
      float p1 = __builtin_amdgcn_exp2f(st1[r]);
      st0[r] = p0; st1[r] = p1;
      tsum += p0 + p1;
    }
    l_run += xhalf_add(tsum);

    short8 pa[4];
#pragma unroll
    for (int kc = 0; kc < 4; ++kc) {
      int a0 = 2 * (kc & 1);
      unsigned x0, x1, y0, y1;
      if (kc < 2) {
        x0 = cvtpk(st0[4 * a0 + 0], st0[4 * a0 + 1]);
        x1 = cvtpk(st0[4 * a0 + 2], st0[4 * a0 + 3]);
        y0 = cvtpk(st0[4 * a0 + 4], st0[4 * a0 + 5]);
        y1 = cvtpk(st0[4 * a0 + 6], st0[4 * a0 + 7]);
      } else {
        x0 = cvtpk(st1[4 * a0 + 0], st1[4 * a0 + 1]);
        x1 = cvtpk(st1[4 * a0 + 2], st1[4 * a0 + 3]);
        y0 = cvtpk(st1[4 * a0 + 4], st1[4 * a0 + 5]);
        y1 = cvtpk(st1[4 * a0 + 6], st1[4 * a0 + 7]);
      }
      asm("v_permlane32_swap_b32 %0, %1" : "+v"(x0), "+v"(y0));
      asm("v_permlane32_swap_b32 %0, %1" : "+v"(x1), "+v"(y1));
      union { unsigned u[4]; short8 s8; } pu;
      pu.u[0] = x0; pu.u[1] = x1; pu.u[2] = y0; pu.u[3] = y1;
      pa[kc] = pu.s8;
    }

    __builtin_amdgcn_s_setprio(1);
#pragma unroll
    for (int nt = 0; nt < 4; ++nt) {
      int row = nt * 32 + ql32;
#pragma unroll
      for (int kc = 0; kc < 4; ++kc) {
        short8 vf = *(const short8*)(vtb + row * 64 + (((kc * 2 + hi) ^ vsw) * 8));
        o[nt] = __builtin_amdgcn_mfma_f32_32x32x16_bf16(vf, pa[kc], o[nt], 0, 0, 0);
      }
    }
    __builtin_amdgcn_s_setprio(0);

    if (kt < 31) {
#pragma unroll
      for (int ps = 0; ps < 2; ++ps) {
        *(short8*)(ksn + kwoff[ps][0]) = va[ps];
        *(short8*)(ksn + kwoff[ps][1]) = vb[ps];
      }
#pragma unroll
      for (int p = 0; p < 4; ++p)
        *(short8*)(vtn + vwoff[p]) = vv[p];
      if (tid < 64) {
        unsigned word = (mreg != 0.f) ? 0u : (unsigned)(unsigned short)negbig;
        *(unsigned*)(kxn + tid * 16) = word;
      }
    }
  }

  float il = 1.0f / l_run;
  short* cp = ctx + ((size_t)(b * TT + qrow)) * DD + h * DKK;
#pragma unroll
  for (int nt = 0; nt < 4; ++nt)
#pragma unroll
    for (int a = 0; a < 4; ++a) {
      short4v sv;
#pragma unroll
      for (int j = 0; j < 4; ++j) sv[j] = f2bf(o[nt][4 * a + j] * il);
      *(short4v*)(cp + nt * 32 + 8 * a + 4 * hi) = sv;
    }
}

extern "C" void kernel_launch(void* const* d_in, const int* in_sizes, int n_in,
                              void* d_out, int out_size, void* d_ws, size_t ws_size,
                              hipStream_t stream) {
  const float* x    = (const float*)d_in[0];
  const float* mask = (const float*)d_in[1];
  const float* Wq   = (const float*)d_in[2];
  const float* Wo   = (const float*)d_in[3];
  char* ws = (char*)d_ws;
  short* xt  = (short*)(ws);
  short* wqb = (short*)(ws + (size_t)16 * 1024 * 1024);
  short* wob = (short*)(ws + (size_t)18 * 1024 * 1024);
  short* qb  = (short*)(ws + (size_t)20 * 1024 * 1024);
  short* ctx = (short*)(ws + (size_t)36 * 1024 * 1024);
  short* qhT = (short*)(ws + (size_t)52 * 1024 * 1024);

  k_prep<<<10240, 256, 0, stream>>>(x, xt, Wq, wqb, Wo, wob);
  k_gemm<0><<<dim3(64, 8), 256, 0, stream>>>(xt, wqb, qb, qhT);
  k_attn<<<dim3(32, 16), 256, 0, stream>>>(qb, qhT, mask, ctx);   // (bh, qt)
  k_gemm<1><<<dim3(8, 64), 256, 0, stream>>>(wob, ctx, d_out, nullptr);
}

// Round 15
// 144.763 us; speedup vs baseline: 1.0339x; 1.0101x over previous
//
#include <hip/hip_runtime.h>

#define TT 2048
#define DD 1024
#define NHH 8
#define DKK 128
// softmax in log2 domain: v_exp_f32 is natively 2^x
#define SCALE2 0.1275174724f          /* (1/sqrt(128)) * log2(e) */

typedef __attribute__((ext_vector_type(8)))  short short8;
typedef __attribute__((ext_vector_type(4)))  short short4v;
typedef __attribute__((ext_vector_type(4)))  float float4v;
typedef __attribute__((ext_vector_type(16))) float float16v;
typedef __attribute__((ext_vector_type(4)))  int   int4v;

__device__ __forceinline__ short f2bf(float f) {
  union { float f; unsigned u; } v; v.f = f;
  unsigned r = v.u + 0x7FFFu + ((v.u >> 16) & 1u);
  return (short)(r >> 16);
}
__device__ __forceinline__ unsigned cvtpk(float lo, float hi) {
  unsigned r;
  asm("v_cvt_pk_bf16_f32 %0, %1, %2" : "=v"(r) : "v"(lo), "v"(hi));
  return r;
}
// pairwise exchange lane l <-> l^32 (VALU pipe, not LDS)
__device__ __forceinline__ float xhalf_add(float x) {
  float y;
  asm("v_mov_b32 %0, %1" : "=v"(y) : "v"(x));
  asm("v_permlane32_swap_b32 %0, %1" : "+v"(x), "+v"(y));
  return x + y;
}
// 16-chunk swizzle for 256B rows
__device__ __forceinline__ int s4(int row) {
  return (row & 7) ^ (((row >> 3) & 3) << 2);
}
// async global->LDS, 16B per lane; lds base is wave-uniform, gsrc per-lane
__device__ __forceinline__ void gl2lds(const void* g, void* l) {
  __builtin_amdgcn_global_load_lds(
      (const __attribute__((address_space(1))) void*)g,
      (__attribute__((address_space(3))) void*)l, 16, 0, 0);
}

// ---- fused prep: xt transpose+cast (blocks 0..8191), Wq cast (8192..9215),
// ---- Wo cast (9216..10239) ----
__global__ __launch_bounds__(256) void k_prep(const float* __restrict__ x,
                                              short* __restrict__ xt,
                                              const float* __restrict__ Wq,
                                              short* __restrict__ wqb,
                                              const float* __restrict__ Wo,
                                              short* __restrict__ wob) {
  int id = blockIdx.x;
  if (id < 8192) {
    __shared__ float tile[32][33];
    int ttile = id & 63, dtile = (id >> 6) & 31, b = id >> 11;
    int d0 = dtile << 5, t0 = ttile << 5;
    int tx = threadIdx.x & 31, ty = threadIdx.x >> 5;
    const float* xp = x + ((size_t)b * DD + d0) * TT + t0;
#pragma unroll
    for (int yy = 0; yy < 32; yy += 8)
      tile[ty + yy][tx] = xp[(size_t)(ty + yy) * TT + tx];
    __syncthreads();
    short* op = xt + ((size_t)b * TT + t0) * DD + d0;
#pragma unroll
    for (int yy = 0; yy < 32; yy += 8)
      op[(size_t)(ty + yy) * DD + tx] = f2bf(tile[tx][ty + yy]);
  } else {
    const float* w = (id < 9216) ? Wq : Wo;
    short* o = (id < 9216) ? wqb : wob;
    int i = (id - 8192 - ((id < 9216) ? 0 : 1024)) * 256 + threadIdx.x;
    float4v v = ((const float4v*)w)[i];
    short4v s;
#pragma unroll
    for (int j = 0; j < 4; ++j) s[j] = f2bf(v[j]);
    ((short4v*)o)[i] = s;
  }
}

// ---- GEMM: C = A(M x 1024) * Bt(N x 1024)^T  — m97 recipe ----
template <int EPI>
__global__ __launch_bounds__(256) void k_gemm(const short* __restrict__ A,
                                              const short* __restrict__ Bt,
                                              void* __restrict__ Cout,
                                              short* __restrict__ qhT) {
  __shared__ __align__(16) short As[128 * 64];
  __shared__ __align__(16) short Bs[128 * 64];
  __shared__ __align__(16) short Ct[(EPI == 0) ? 128 * 136 : 1];
  const int K = 1024;
  int tm = blockIdx.x * 128, tn = blockIdx.y * 128;
  int tid = threadIdx.x, lane = tid & 63, w = tid >> 6;
  int wm = (w >> 1) * 64, wn = (w & 1) * 64;
  int ql = lane & 15, g = lane >> 4;

  int srow[4], scol[4];
#pragma unroll
  for (int c = 0; c < 4; ++c) {
    int cg = w * 4 + c;
    int r = cg * 8 + (lane >> 3);
    srow[c] = r;
    scol[c] = ((lane & 7) ^ (r & 7)) * 8;
  }

  float4v acc[4][4];
#pragma unroll
  for (int mt = 0; mt < 4; ++mt)
#pragma unroll
    for (int nt = 0; nt < 4; ++nt) acc[mt][nt] = (float4v){0.f, 0.f, 0.f, 0.f};

  for (int k0 = 0; k0 < K; k0 += 64) {
    __syncthreads();
#pragma unroll
    for (int c = 0; c < 4; ++c) {
      int cg = w * 4 + c;
      gl2lds(A + (size_t)(tm + srow[c]) * K + k0 + scol[c], As + cg * 512);
      gl2lds(Bt + (size_t)(tn + srow[c]) * K + k0 + scol[c], Bs + cg * 512);
    }
    __syncthreads();
#pragma unroll
    for (int k4 = 0; k4 < 2; ++k4) {
      short8 af[4], bfr[4];
#pragma unroll
      for (int mt = 0; mt < 4; ++mt) {
        int row = wm + mt * 16 + ql;
        af[mt] = *(const short8*)(As + row * 64 + (((k4 * 4 + g) ^ (ql & 7)) * 8));
      }
#pragma unroll
      for (int nt = 0; nt < 4; ++nt) {
        int row = wn + nt * 16 + ql;
        bfr[nt] = *(const short8*)(Bs + row * 64 + (((k4 * 4 + g) ^ (ql & 7)) * 8));
      }
#pragma unroll
      for (int mt = 0; mt < 4; ++mt)
#pragma unroll
        for (int nt = 0; nt < 4; ++nt)
          acc[mt][nt] = __builtin_amdgcn_mfma_f32_16x16x32_bf16(af[mt], bfr[nt],
                                                                acc[mt][nt], 0, 0, 0);
    }
  }

  if (EPI == 1) {
#pragma unroll
    for (int mt = 0; mt < 4; ++mt)
#pragma unroll
      for (int nt = 0; nt < 4; ++nt)
#pragma unroll
        for (int r = 0; r < 4; ++r) {
          int m = tm + wm + mt * 16 + g * 4 + r;
          int n = tn + wn + nt * 16 + ql;
          int b = n >> 11, t = n & 2047;
          ((float*)Cout)[((size_t)b * 1024 + m) * 2048 + t] = acc[mt][nt][r];
        }
  } else {
    __syncthreads();
#pragma unroll
    for (int mt = 0; mt < 4; ++mt)
#pragma unroll
      for (int nt = 0; nt < 4; ++nt)
#pragma unroll
        for (int r = 0; r < 4; ++r)
          Ct[(wm + mt * 16 + g * 4 + r) * 136 + wn + nt * 16 + ql] =
              f2bf(acc[mt][nt][r]);
    __syncthreads();
    int bb = tm >> 11, t0 = tm & 2047;
    short* qb = (short*)Cout;
    {
      int m = tid >> 1, c0 = (tid & 1) * 64;
      short* dst = qb + (size_t)(tm + m) * 1024 + tn + c0;
      const short* src = Ct + m * 136 + c0;
#pragma unroll
      for (int i = 0; i < 8; ++i)
        *(short8*)(dst + i * 8) = *(const short8*)(src + i * 8);
    }
    {
      int n = tid >> 1, m0 = (tid & 1) * 64;
      short* dst = qhT + ((size_t)(bb * DD + tn + n)) * TT + t0 + m0;
#pragma unroll
      for (int i = 0; i < 8; ++i) {
        short8 v;
#pragma unroll
        for (int j = 0; j < 8; ++j) v[j] = Ct[(m0 + i * 8 + j) * 136 + n];
        *(short8*)(dst + i * 8) = v;
      }
    }
  }
}

// ---- fused masked self-attention: tile-level software pipeline ----
// grid (bh, qt). Per iter: QK[t] -> PV[t-1] (pa from prev iter, Vt in buf^1)
// -> softmax[t]->pa -> barrier -> stage[t+1]. No cross-tile dep besides
// l_run/O (no max-tracking), so PV defers one tile cleanly.
__global__ __launch_bounds__(256, 2) void k_attn(const short* __restrict__ q,
                                                 const short* __restrict__ qhT,
                                                 const float* __restrict__ mask,
                                                 short* __restrict__ ctx) {
  __shared__ __align__(16) short Ks[2][64 * 128];
  __shared__ __align__(16) short Vt[2][128 * 64];
  __shared__ __align__(16) short Kx[2][64 * 16];

  int bh = blockIdx.x, qt = blockIdx.y;   // (bh, qt) for XCD-L2 locality
  int b = bh >> 3, h = bh & 7;
  int tid = threadIdx.x, lane = tid & 63, w = tid >> 6;
  int ql32 = lane & 31, hi = lane >> 5;
  int csw = s4(ql32);
  int vsw = ql32 & 7;
  short negbig = f2bf(-1e30f);

  int qrow = qt * 128 + w * 32 + ql32;
  const short* qp = q + ((size_t)(b * TT + qrow)) * DD + h * DKK;
  short8 qf[8];
#pragma unroll
  for (int kc8 = 0; kc8 < 8; ++kc8)
    qf[kc8] = *(const short8*)(qp + kc8 * 16 + hi * 8);
  float rm = mask[(size_t)b * TT + qrow];

  float qs = SCALE2 * rm;
#pragma unroll
  for (int kc8 = 0; kc8 < 8; ++kc8) {
    union { short8 s; unsigned u[4]; } a;
    a.s = qf[kc8];
#pragma unroll
    for (int j = 0; j < 4; ++j) {
      union { unsigned u; float f; } lo, hh;
      lo.u = a.u[j] << 16;
      hh.u = a.u[j] & 0xFFFF0000u;
      a.u[j] = cvtpk(lo.f * qs, hh.f * qs);
    }
    qf[kc8] = a.s;
  }
  short8 bext = (short8)0;
  if (hi == 0) bext[0] = (rm != 0.f) ? (short)0x3F80 : (short)0;

  int oc = tid & 15, r2 = tid >> 4;
  const short* kbase_g = q + ((size_t)b * TT) * DD + h * DKK + oc * 8;
  const short* vbase_g = qhT + ((size_t)(b * DD + h * DKK)) * TT;
  int vd[4], vko[4], vwoff[4];
#pragma unroll
  for (int p = 0; p < 4; ++p) {
    int idx = p * 256 + tid;
    vd[p] = idx >> 3;
    vko[p] = idx & 7;
    vwoff[p] = vd[p] * 64 + ((vko[p] ^ (vd[p] & 7)) * 8);
  }
  int kwoff[2][2];
#pragma unroll
  for (int ps = 0; ps < 2; ++ps) {
    int ra = 2 * r2 + 32 * ps, rb = ra + 1;
    kwoff[ps][0] = ra * 128 + ((oc ^ s4(ra)) * 8);
    kwoff[ps][1] = rb * 128 + ((oc ^ s4(rb)) * 8);
  }

  // prologue: load tile 0 into regs, stage into buf 0
  short8 va[2], vb[2], vv[4];
#pragma unroll
  for (int ps = 0; ps < 2; ++ps) {
    const short* kp = kbase_g + (size_t)(2 * r2 + 32 * ps) * DD;
    va[ps] = *(const short8*)(kp);
    vb[ps] = *(const short8*)(kp + DD);
  }
#pragma unroll
  for (int p = 0; p < 4; ++p)
    vv[p] = *(const short8*)(vbase_g + (size_t)vd[p] * TT + vko[p] * 8);
  float mreg = mask[(size_t)b * TT + lane];

#pragma unroll
  for (int ps = 0; ps < 2; ++ps) {
    *(short8*)(Ks[0] + kwoff[ps][0]) = va[ps];
    *(short8*)(Ks[0] + kwoff[ps][1]) = vb[ps];
  }
#pragma unroll
  for (int p = 0; p < 4; ++p)
    *(short8*)(Vt[0] + vwoff[p]) = vv[p];
  if (tid < 128) {
    short8 z = (short8)0;
    if (tid < 64) z[0] = (mreg != 0.f) ? (short)0 : negbig;
    *(short8*)(&Kx[0][0] + tid * 16) = z;
    *(short8*)(&Kx[0][0] + tid * 16 + 8) = (short8)0;
  }

  float l_run = 0.f;
  float16v o[4];
#pragma unroll
  for (int nt = 0; nt < 4; ++nt)
#pragma unroll
    for (int r = 0; r < 16; ++r) o[nt][r] = 0.f;
  short8 pa[4];   // P fragments of tile kt-1, live across iterations

  for (int kt = 0; kt < 32; ++kt) {
    int cur = kt & 1;
    const short* ksb = Ks[cur];
    const short* kxb = Kx[cur];
    const short* vtb_prev = Vt[cur ^ 1];   // V of tile kt-1
    short* ksn = Ks[cur ^ 1];
    short* vtn = Vt[cur ^ 1];
    short* kxn = Kx[cur ^ 1];

    __syncthreads();   // buf[cur] (tile kt) fully staged

    // ---- A: S^T = K * Q^T for tile kt (+ mask-bias ext MFMA) ----
    float16v st0, st1;
#pragma unroll
    for (int r = 0; r < 16; ++r) { st0[r] = 0.f; st1[r] = 0.f; }
    __builtin_amdgcn_s_setprio(1);
    {
      short8 ax0 = *(const short8*)(kxb + ql32 * 16 + hi * 8);
      short8 ax1 = *(const short8*)(kxb + (32 + ql32) * 16 + hi * 8);
      st0 = __builtin_amdgcn_mfma_f32_32x32x16_bf16(ax0, bext, st0, 0, 0, 0);
      st1 = __builtin_amdgcn_mfma_f32_32x32x16_bf16(ax1, bext, st1, 0, 0, 0);
    }
#pragma unroll
    for (int kc8 = 0; kc8 < 8; ++kc8) {
      int csk = ((kc8 * 2 + hi) ^ csw) * 8;
      short8 kf0 = *(const short8*)(ksb + ql32 * 128 + csk);
      short8 kf1 = *(const short8*)(ksb + (32 + ql32) * 128 + csk);
      st0 = __builtin_amdgcn_mfma_f32_32x32x16_bf16(kf0, qf[kc8], st0, 0, 0, 0);
      st1 = __builtin_amdgcn_mfma_f32_32x32x16_bf16(kf1, qf[kc8], st1, 0, 0, 0);
    }
    __builtin_amdgcn_s_setprio(0);

    // issue next-tile global loads (L2-resident; land well before stage D)
    if (kt < 31) {
      int kb0n = (kt + 1) * 64;
      const short* kpn = kbase_g + (size_t)kb0n * DD;
#pragma unroll
      for (int ps = 0; ps < 2; ++ps) {
        const short* kp = kpn + (size_t)(2 * r2 + 32 * ps) * DD;
        va[ps] = *(const short8*)(kp);
        vb[ps] = *(const short8*)(kp + DD);
      }
#pragma unroll
      for (int p = 0; p < 4; ++p)
        vv[p] = *(const short8*)(vbase_g + (size_t)vd[p] * TT + kb0n + vko[p] * 8);
      mreg = mask[(size_t)b * TT + kb0n + lane];
    }

    // ---- C: O^T += V^T[kt-1] * P^T[kt-1]  (pa from previous iteration;
    //      MFMA chains independent of A's -> pipe overlap) ----
    if (kt > 0) {
      __builtin_amdgcn_s_setprio(1);
#pragma unroll
      for (int nt = 0; nt < 4; ++nt) {
        int row = nt * 32 + ql32;
#pragma unroll
        for (int kc = 0; kc < 4; ++kc) {
          short8 vf = *(const short8*)(vtb_prev + row * 64 + (((kc * 2 + hi) ^ vsw) * 8));
          o[nt] = __builtin_amdgcn_mfma_f32_32x32x16_bf16(vf, pa[kc], o[nt], 0, 0, 0);
        }
      }
      __builtin_amdgcn_s_setprio(0);
    }

    // ---- B: softmax[kt] -> pa (overwrites AFTER C consumed old pa) ----
    float tsum = 0.f;
#pragma unroll
    for (int r = 0; r < 16; ++r) {
      float p0 = __builtin_amdgcn_exp2f(st0[r]);
      float p1 = __builtin_amdgcn_exp2f(st1[r]);
      st0[r] = p0; st1[r] = p1;
      tsum += p0 + p1;
    }
    l_run += xhalf_add(tsum);

#pragma unroll
    for (int kc = 0; kc < 4; ++kc) {
      int a0 = 2 * (kc & 1);
      unsigned x0, x1, y0, y1;
      if (kc < 2) {
        x0 = cvtpk(st0[4 * a0 + 0], st0[4 * a0 + 1]);
        x1 = cvtpk(st0[4 * a0 + 2], st0[4 * a0 + 3]);
        y0 = cvtpk(st0[4 * a0 + 4], st0[4 * a0 + 5]);
        y1 = cvtpk(st0[4 * a0 + 6], st0[4 * a0 + 7]);
      } else {
        x0 = cvtpk(st1[4 * a0 + 0], st1[4 * a0 + 1]);
        x1 = cvtpk(st1[4 * a0 + 2], st1[4 * a0 + 3]);
        y0 = cvtpk(st1[4 * a0 + 4], st1[4 * a0 + 5]);
        y1 = cvtpk(st1[4 * a0 + 6], st1[4 * a0 + 7]);
      }
      asm("v_permlane32_swap_b32 %0, %1" : "+v"(x0), "+v"(y0));
      asm("v_permlane32_swap_b32 %0, %1" : "+v"(x1), "+v"(y1));
      union { unsigned u[4]; short8 s8; } pu;
      pu.u[0] = x0; pu.u[1] = x1; pu.u[2] = y0; pu.u[3] = y1;
      pa[kc] = pu.s8;
    }

    __syncthreads();   // all waves done reading buf[cur^1] (phase C)

    // ---- D: stage tile kt+1 into buf[cur^1] ----
    if (kt < 31) {
#pragma unroll
      for (int ps = 0; ps < 2; ++ps) {
        *(short8*)(ksn + kwoff[ps][0]) = va[ps];
        *(short8*)(ksn + kwoff[ps][1]) = vb[ps];
      }
#pragma unroll
      for (int p = 0; p < 4; ++p)
        *(short8*)(vtn + vwoff[p]) = vv[p];
      if (tid < 64) {
        unsigned word = (mreg != 0.f) ? 0u : (unsigned)(unsigned short)negbig;
        *(unsigned*)(kxn + tid * 16) = word;
      }
    }
  }

  // ---- pipeline epilogue: PV[31] (tile 31 lives in buf[1]) ----
  {
    const short* vtb = Vt[1];
#pragma unroll
    for (int nt = 0; nt < 4; ++nt) {
      int row = nt * 32 + ql32;
#pragma unroll
      for (int kc = 0; kc < 4; ++kc) {
        short8 vf = *(const short8*)(vtb + row * 64 + (((kc * 2 + hi) ^ vsw) * 8));
        o[nt] = __builtin_amdgcn_mfma_f32_32x32x16_bf16(vf, pa[kc], o[nt], 0, 0, 0);
      }
    }
  }

  float il = 1.0f / l_run;
  short* cp = ctx + ((size_t)(b * TT + qrow)) * DD + h * DKK;
#pragma unroll
  for (int nt = 0; nt < 4; ++nt)
#pragma unroll
    for (int a = 0; a < 4; ++a) {
      short4v sv;
#pragma unroll
      for (int j = 0; j < 4; ++j) sv[j] = f2bf(o[nt][4 * a + j] * il);
      *(short4v*)(cp + nt * 32 + 8 * a + 4 * hi) = sv;
    }
}

extern "C" void kernel_launch(void* const* d_in, const int* in_sizes, int n_in,
                              void* d_out, int out_size, void* d_ws, size_t ws_size,
                              hipStream_t stream) {
  const float* x    = (const float*)d_in[0];
  const float* mask = (const float*)d_in[1];
  const float* Wq   = (const float*)d_in[2];
  const float* Wo   = (const float*)d_in[3];
  char* ws = (char*)d_ws;
  short* xt  = (short*)(ws);
  short* wqb = (short*)(ws + (size_t)16 * 1024 * 1024);
  short* wob = (short*)(ws + (size_t)18 * 1024 * 1024);
  short* qb  = (short*)(ws + (size_t)20 * 1024 * 1024);
  short* ctx = (short*)(ws + (size_t)36 * 1024 * 1024);
  short* qhT = (short*)(ws + (size_t)52 * 1024 * 1024);

  k_prep<<<10240, 256, 0, stream>>>(x, xt, Wq, wqb, Wo, wob);
  k_gemm<0><<<dim3(64, 8), 256, 0, stream>>>(xt, wqb, qb, qhT);
  k_attn<<<dim3(32, 16), 256, 0, stream>>>(qb, qhT, mask, ctx);
  k_gemm<1><<<dim3(8, 64), 256, 0, stream>>>(wob, ctx, d_out, nullptr);
}